// Round 14
// baseline (99.021 us; speedup 1.0000x reference)
//
#include <hip/hip_runtime.h>

// Poincare contrastive loss, N=4096, D=8, TEMP=0.5.
// sim[i][j] = 1/(1+arcosh(x_ij)), x_ij = 1 + 2*sqdist/((1-sqc_i)(1-sqc_j))
// Rewrite: x = 1 + P_i . Q_j  (10-term dot)
//   Q_j = [z_j(8), inv_j, inv_j*raw_j],  inv = 1/(1-min(raw,BOUNDARY))
//   P_i = [-4*inv_i*z_i(8), 2*inv_i*raw_i, 2*inv_i]
// loss = mean_i -(2*sim[i,partner] - log(sum_{j!=i} exp(2*sim[i][j])))
//
// SYMMETRY: packed upper-triangle grid of 2176 tiles (i-tile 512 = 256thr x
// R=2 packed-fp32 rows, j-chunk 32). Q_j wave-uniform -> SGPR s_load.
// Round-13 lesson: launch_bounds 2nd arg is a MIN; the scheduler still
// pressure-minimizes to VGPR=24 (p2:20 + acc:2 + ONE chain temp:2) and
// serializes all column chains. Round-14: amdgpu_waves_per_eu(4,4) caps the
// occupancy target -> scheduler may spend up to 128 VGPRs on real ILP
// (4 concurrent column chains = 8 scalar trans streams in flight).
// DPP wave reduce -> lane 63 -> fire-and-forget global atomic per column.
// 3 stream ops: prep (zeroes denom+out) -> pair -> reduce (32 blk, DPP).

#define D 8
#define QS 12                // padded Q stride (floats) -> 48B, 16B-aligned
#define TWO_N 8192
#define HALF_N 4096
constexpr int BLOCK = 256;
constexpr int JC    = 32;    // j-chunk per tile
constexpr int NTILE = 2176;  // sum_{b=0}^{15} (256 - 16b)
#define BOUNDARY (1.0f - 1e-5f)
#define LN2 0.6931471805599453f
#define TWO_LOG2E 2.8853900817779268f   // 2*log2(e)

typedef float f32x2 __attribute__((ext_vector_type(2)));

__device__ __forceinline__ float frcp(float x)  { return __builtin_amdgcn_rcpf(x); }
__device__ __forceinline__ float fsqrt(float x) { return __builtin_amdgcn_sqrtf(x); }
__device__ __forceinline__ float flog2(float x) { return __builtin_amdgcn_logf(x); }
__device__ __forceinline__ float fexp2(float x) { return __builtin_amdgcn_exp2f(x); }
__device__ __forceinline__ f32x2 splat(float v) { return (f32x2){v, v}; }

// DPP wave64 sum: result in lane 63.
__device__ __forceinline__ float dpp_wave_sum(float v) {
    int x;
    x = __builtin_amdgcn_update_dpp(0, __float_as_int(v), 0x111, 0xf, 0xf, false); // row_shr:1
    v += __int_as_float(x);
    x = __builtin_amdgcn_update_dpp(0, __float_as_int(v), 0x112, 0xf, 0xf, false); // row_shr:2
    v += __int_as_float(x);
    x = __builtin_amdgcn_update_dpp(0, __float_as_int(v), 0x114, 0xf, 0xe, false); // row_shr:4
    v += __int_as_float(x);
    x = __builtin_amdgcn_update_dpp(0, __float_as_int(v), 0x118, 0xf, 0xc, false); // row_shr:8
    v += __int_as_float(x);
    x = __builtin_amdgcn_update_dpp(0, __float_as_int(v), 0x142, 0xa, 0xf, false); // row_bcast:15
    v += __int_as_float(x);
    x = __builtin_amdgcn_update_dpp(0, __float_as_int(v), 0x143, 0xc, 0xf, false); // row_bcast:31
    v += __int_as_float(x);
    return v;   // lane 63 = full sum
}

// ---- prep: Q[row] = [z(8), inv, inv*raw, 0, 0]; zero denom + out ----
__global__ __launch_bounds__(256) void prep_kernel(
    const float* __restrict__ zi, const float* __restrict__ zj,
    float* __restrict__ q, float* __restrict__ denom, float* __restrict__ out)
{
    const int row = blockIdx.x * 256 + threadIdx.x;
    const float* src = (row < HALF_N) ? (zi + (size_t)row * D)
                                      : (zj + (size_t)(row - HALF_N) * D);
    float4 a = *(const float4*)(src);
    float4 b = *(const float4*)(src + 4);
    float raw = a.x*a.x + a.y*a.y + a.z*a.z + a.w*a.w
              + b.x*b.x + b.y*b.y + b.z*b.z + b.w*b.w;
    float inv = frcp(1.0f - fminf(raw, BOUNDARY));
    float* dst = q + (size_t)row * QS;
    *(float4*)(dst)     = a;
    *(float4*)(dst + 4) = b;
    *(float4*)(dst + 8) = make_float4(inv, inv * raw, 0.0f, 0.0f);
    denom[row] = 0.0f;
    if (row == 0) out[0] = 0.0f;
}

// one column's dot chain; qq is WAVE-UNIFORM -> s_load operands
__device__ __forceinline__ f32x2 pair_col(const f32x2* __restrict__ p2,
                                          const float* __restrict__ qq)
{
    float4 a  = *(const float4*)(qq);
    float4 bb = *(const float4*)(qq + 4);
    float2 c  = *(const float2*)(qq + 8);
    f32x2 x = splat(1.0f);
    x = __builtin_elementwise_fma(p2[0], splat(a.x),  x);
    x = __builtin_elementwise_fma(p2[1], splat(a.y),  x);
    x = __builtin_elementwise_fma(p2[2], splat(a.z),  x);
    x = __builtin_elementwise_fma(p2[3], splat(a.w),  x);
    x = __builtin_elementwise_fma(p2[4], splat(bb.x), x);
    x = __builtin_elementwise_fma(p2[5], splat(bb.y), x);
    x = __builtin_elementwise_fma(p2[6], splat(bb.z), x);
    x = __builtin_elementwise_fma(p2[7], splat(bb.w), x);
    x = __builtin_elementwise_fma(p2[8], splat(c.x),  x);
    x = __builtin_elementwise_fma(p2[9], splat(c.y),  x);
    return x;
}

__device__ __forceinline__ f32x2 finish_col(f32x2 x)
{
    f32x2 tt = __builtin_elementwise_fma(x, x, splat(-1.0f));
    tt = __builtin_elementwise_max(tt, splat(0.0f));
    f32x2 s  = (f32x2){fsqrt(tt.x), fsqrt(tt.y)};
    f32x2 y  = x + s;
    f32x2 L  = (f32x2){flog2(y.x), flog2(y.y)};
    f32x2 dd = __builtin_elementwise_fma(L, splat(LN2), splat(1.0f));
    f32x2 sim = (f32x2){frcp(dd.x), frcp(dd.y)};
    f32x2 arg = sim * splat(TWO_LOG2E);
    return (f32x2){fexp2(arg.x), fexp2(arg.y)};
}

// ---- symmetric pair kernel: SGPR Q, 4-col interleave, waves_per_eu(4,4) ----
__global__
__attribute__((amdgpu_flat_work_group_size(256, 256)))
__attribute__((amdgpu_waves_per_eu(4, 4)))
void pair_kernel(const float* __restrict__ q, float* __restrict__ denom)
{
    const int tid = threadIdx.x;

    // tile decode: t -> (b = i-block of 512 rows, jbase)
    const int t = blockIdx.x;
    int b = 0;
    #pragma unroll
    for (int k = 1; k < 16; ++k)
        b += (t >= (256 * k - 8 * k * (k - 1))) ? 1 : 0;
    const int Fb    = 256 * b - 8 * b * (b - 1);
    const int ibase = 512 * b;
    const int jbase = ibase + 32 * (t - Fb);
    const bool diag = (jbase < ibase + 512);

    const float* qj = q + (size_t)jbase * QS;     // wave-uniform base

    // own two rows -> packed P: p2[k] = {P_row0[k], P_row1[k]}
    const int irow0 = ibase + tid;
    const int irow1 = ibase + tid + BLOCK;
    f32x2 p2[10];
    {
        const float* q0 = q + (size_t)irow0 * QS;
        const float* q1 = q + (size_t)irow1 * QS;
        float4 a0 = *(const float4*)(q0), b0 = *(const float4*)(q0 + 4);
        float4 c0 = *(const float4*)(q0 + 8);
        float4 a1 = *(const float4*)(q1), b1 = *(const float4*)(q1 + 4);
        float4 c1 = *(const float4*)(q1 + 8);
        float m0 = -4.0f * c0.x, m1 = -4.0f * c1.x;
        p2[0] = (f32x2){m0 * a0.x, m1 * a1.x};
        p2[1] = (f32x2){m0 * a0.y, m1 * a1.y};
        p2[2] = (f32x2){m0 * a0.z, m1 * a1.z};
        p2[3] = (f32x2){m0 * a0.w, m1 * a1.w};
        p2[4] = (f32x2){m0 * b0.x, m1 * b1.x};
        p2[5] = (f32x2){m0 * b0.y, m1 * b1.y};
        p2[6] = (f32x2){m0 * b0.z, m1 * b1.z};
        p2[7] = (f32x2){m0 * b0.w, m1 * b1.w};
        p2[8] = (f32x2){2.0f * c0.y, 2.0f * c1.y};
        p2[9] = (f32x2){2.0f * c0.x, 2.0f * c1.x};
    }
    f32x2 acc2 = splat(0.0f);

    #pragma unroll 2
    for (int jp = 0; jp < JC / 4; ++jp) {
        const int jj0 = 4 * jp;

        // four independent dot chains (pk-FMA), then four trans chains
        f32x2 x0 = pair_col(p2, qj + (jj0 + 0) * QS);
        f32x2 x1 = pair_col(p2, qj + (jj0 + 1) * QS);
        f32x2 x2 = pair_col(p2, qj + (jj0 + 2) * QS);
        f32x2 x3 = pair_col(p2, qj + (jj0 + 3) * QS);
        f32x2 e0 = finish_col(x0);
        f32x2 e1 = finish_col(x1);
        f32x2 e2 = finish_col(x2);
        f32x2 e3 = finish_col(x3);

        if (diag) {
            const int j0 = jbase + jj0;
            e0.x = (j0 + 0 > irow0) ? e0.x : 0.0f;
            e0.y = (j0 + 0 > irow1) ? e0.y : 0.0f;
            e1.x = (j0 + 1 > irow0) ? e1.x : 0.0f;
            e1.y = (j0 + 1 > irow1) ? e1.y : 0.0f;
            e2.x = (j0 + 2 > irow0) ? e2.x : 0.0f;
            e2.y = (j0 + 2 > irow1) ? e2.y : 0.0f;
            e3.x = (j0 + 3 > irow0) ? e3.x : 0.0f;
            e3.y = (j0 + 3 > irow1) ? e3.y : 0.0f;
        }
        acc2 += e0; acc2 += e1; acc2 += e2; acc2 += e3;

        float c0 = dpp_wave_sum(e0.x + e0.y);
        float c1 = dpp_wave_sum(e1.x + e1.y);
        float c2 = dpp_wave_sum(e2.x + e2.y);
        float c3 = dpp_wave_sum(e3.x + e3.y);
        if ((tid & 63) == 63) {                  // fire-and-forget column adds
            atomicAdd(&denom[jbase + jj0 + 0], c0);
            atomicAdd(&denom[jbase + jj0 + 1], c1);
            atomicAdd(&denom[jbase + jj0 + 2], c2);
            atomicAdd(&denom[jbase + jj0 + 3], c3);
        }
    }

    atomicAdd(&denom[irow0], acc2.x);
    atomicAdd(&denom[irow1], acc2.y);
}

// ---- epilogue: 32 blocks x 256, one row/thread, DPP wave sums ----
__global__ __launch_bounds__(256) void reduce_kernel(
    const float* __restrict__ zi, const float* __restrict__ zj,
    const float* __restrict__ denom, float* __restrict__ out)
{
    const int tid = threadIdx.x;
    const int i   = blockIdx.x * 256 + tid;

    const int base = (i < HALF_N) ? i : (i - HALF_N);
    const float* pa = (i < HALF_N) ? (zi + (size_t)base * D) : (zj + (size_t)base * D);
    const float* pb = (i < HALF_N) ? (zj + (size_t)base * D) : (zi + (size_t)base * D);
    float4 a0 = *(const float4*)(pa), a1 = *(const float4*)(pa + 4);
    float4 b0 = *(const float4*)(pb), b1 = *(const float4*)(pb + 4);
    float rawa = a0.x*a0.x + a0.y*a0.y + a0.z*a0.z + a0.w*a0.w
               + a1.x*a1.x + a1.y*a1.y + a1.z*a1.z + a1.w*a1.w;
    float rawb = b0.x*b0.x + b0.y*b0.y + b0.z*b0.z + b0.w*b0.w
               + b1.x*b1.x + b1.y*b1.y + b1.z*b1.z + b1.w*b1.w;
    float dot  = a0.x*b0.x + a0.y*b0.y + a0.z*b0.z + a0.w*b0.w
               + a1.x*b1.x + a1.y*b1.y + a1.z*b1.z + a1.w*b1.w;
    float sqd  = fmaxf(rawa + rawb - 2.0f * dot, 0.0f);
    float inva = frcp(1.0f - fminf(rawa, BOUNDARY));
    float invb = frcp(1.0f - fminf(rawb, BOUNDARY));
    float x    = fmaf(2.0f * sqd, inva * invb, 1.0f);
    float t    = fmaf(x, x, -1.0f);
    float s    = fsqrt(fmaxf(t, 0.0f));
    float dist = flog2(x + s) * LN2;
    float sim  = frcp(1.0f + dist);               // positive pair similarity
    float dlog = flog2(denom[i]) * LN2;           // self already excluded
    float term = -(2.0f * sim - dlog);

    float wsum = dpp_wave_sum(term);
    if ((tid & 63) == 63)
        atomicAdd(out, wsum * (1.0f / (float)TWO_N));
}

extern "C" void kernel_launch(void* const* d_in, const int* in_sizes, int n_in,
                              void* d_out, int out_size, void* d_ws, size_t ws_size,
                              hipStream_t stream) {
    const float* zi = (const float*)d_in[0];
    const float* zj = (const float*)d_in[1];

    float* denom = (float*)d_ws;                  // [8192]
    float* q     = denom + TWO_N;                 // [8192 * 12]

    prep_kernel<<<TWO_N / 256, 256, 0, stream>>>(zi, zj, q, denom, (float*)d_out);

    pair_kernel<<<NTILE, BLOCK, 0, stream>>>(q, denom);

    reduce_kernel<<<TWO_N / 256, 256, 0, stream>>>(zi, zj, denom, (float*)d_out);
}

// Round 15
// 94.212 us; speedup vs baseline: 1.0510x; 1.0510x over previous
//
#include <hip/hip_runtime.h>

// Poincare contrastive loss, N=4096, D=8, TEMP=0.5.
// sim[i][j] = 1/(1+arcosh(x_ij)), x_ij = 1 + 2*sqdist/((1-sqc_i)(1-sqc_j))
// Rewrite: x = 1 + P_i . Q_j  (10-term dot)
//   Q_j = [z_j(8), inv_j, inv_j*raw_j],  inv = 1/(1-min(raw,BOUNDARY))
//   P_i = [-4*inv_i*z_i(8), 2*inv_i*raw_i, 2*inv_i]
// loss = mean_i -(2*sim[i,partner] - log(sum_{j!=i} exp(2*sim[i][j])))
//
// ROUND-15: revert to round-11, the empirical best (94.26 us total,
// pair 41.1 us). Rounds 8-14 established invariance: pair wall 41-48 us
// across ILP 1/2/4-col, VGPR 20-52, LDS vs SGPR Q, shfl vs DPP, occupancy
// bounds 4/8 -> structural floor for this decomposition. Non-pair ~53 us
// fixed (invariant to dispatch count/structure, rounds 1-14).
//
// SYMMETRY: packed upper-triangle grid of 2176 tiles (i-tile 512 = 256thr x
// R=2 packed-fp32 rows, j-chunk 32) -> 8.5 blocks/CU residency+backfill.
// Packed-fp32 (v_pk_fma_f32) full-rate math; scalar trans x2 per f32x2.
// Per-column DPP wave reduce -> lane 63 -> LDS accumulate -> 1 atomic/(blk,j).
// 3 stream ops: prep (also zeroes denom+out) -> pair -> reduce (8 blocks).

#define D 8
#define QS 12                // padded Q stride (floats) -> 48B, 16B-aligned
#define TWO_N 8192
#define HALF_N 4096
constexpr int BLOCK = 256;
constexpr int JC    = 32;    // j-chunk staged in LDS per block
constexpr int NTILE = 2176;  // sum_{b=0}^{15} (256 - 16b)
#define BOUNDARY (1.0f - 1e-5f)
#define LN2 0.6931471805599453f
#define TWO_LOG2E 2.8853900817779268f   // 2*log2(e)

typedef float f32x2 __attribute__((ext_vector_type(2)));

__device__ __forceinline__ float frcp(float x)  { return __builtin_amdgcn_rcpf(x); }
__device__ __forceinline__ float fsqrt(float x) { return __builtin_amdgcn_sqrtf(x); }
__device__ __forceinline__ float flog2(float x) { return __builtin_amdgcn_logf(x); }
__device__ __forceinline__ float fexp2(float x) { return __builtin_amdgcn_exp2f(x); }
__device__ __forceinline__ f32x2 splat(float v) { return (f32x2){v, v}; }

// DPP wave64 sum: result in lane 63.
__device__ __forceinline__ float dpp_wave_sum(float v) {
    int x;
    x = __builtin_amdgcn_update_dpp(0, __float_as_int(v), 0x111, 0xf, 0xf, false); // row_shr:1
    v += __int_as_float(x);
    x = __builtin_amdgcn_update_dpp(0, __float_as_int(v), 0x112, 0xf, 0xf, false); // row_shr:2
    v += __int_as_float(x);
    x = __builtin_amdgcn_update_dpp(0, __float_as_int(v), 0x114, 0xf, 0xe, false); // row_shr:4
    v += __int_as_float(x);
    x = __builtin_amdgcn_update_dpp(0, __float_as_int(v), 0x118, 0xf, 0xc, false); // row_shr:8
    v += __int_as_float(x);
    x = __builtin_amdgcn_update_dpp(0, __float_as_int(v), 0x142, 0xa, 0xf, false); // row_bcast:15
    v += __int_as_float(x);
    x = __builtin_amdgcn_update_dpp(0, __float_as_int(v), 0x143, 0xc, 0xf, false); // row_bcast:31
    v += __int_as_float(x);
    return v;   // lane 63 = full sum
}

// ---- prep: Q[row] = [z(8), inv, inv*raw, 0, 0]; zero denom + out ----
__global__ __launch_bounds__(256) void prep_kernel(
    const float* __restrict__ zi, const float* __restrict__ zj,
    float* __restrict__ q, float* __restrict__ denom, float* __restrict__ out)
{
    const int row = blockIdx.x * 256 + threadIdx.x;
    const float* src = (row < HALF_N) ? (zi + (size_t)row * D)
                                      : (zj + (size_t)(row - HALF_N) * D);
    float4 a = *(const float4*)(src);
    float4 b = *(const float4*)(src + 4);
    float raw = a.x*a.x + a.y*a.y + a.z*a.z + a.w*a.w
              + b.x*b.x + b.y*b.y + b.z*b.z + b.w*b.w;
    float inv = frcp(1.0f - fminf(raw, BOUNDARY));
    float* dst = q + (size_t)row * QS;
    *(float4*)(dst)     = a;
    *(float4*)(dst + 4) = b;
    *(float4*)(dst + 8) = make_float4(inv, inv * raw, 0.0f, 0.0f);
    denom[row] = 0.0f;
    if (row == 0) out[0] = 0.0f;
}

// one column's full chain, split for interleaving
__device__ __forceinline__ f32x2 pair_col(const f32x2* __restrict__ p2,
                                          const float* __restrict__ qq)
{
    float4 a  = *(const float4*)(qq);
    float4 bb = *(const float4*)(qq + 4);
    float2 c  = *(const float2*)(qq + 8);
    f32x2 x = splat(1.0f);
    x = __builtin_elementwise_fma(p2[0], splat(a.x),  x);
    x = __builtin_elementwise_fma(p2[1], splat(a.y),  x);
    x = __builtin_elementwise_fma(p2[2], splat(a.z),  x);
    x = __builtin_elementwise_fma(p2[3], splat(a.w),  x);
    x = __builtin_elementwise_fma(p2[4], splat(bb.x), x);
    x = __builtin_elementwise_fma(p2[5], splat(bb.y), x);
    x = __builtin_elementwise_fma(p2[6], splat(bb.z), x);
    x = __builtin_elementwise_fma(p2[7], splat(bb.w), x);
    x = __builtin_elementwise_fma(p2[8], splat(c.x),  x);
    x = __builtin_elementwise_fma(p2[9], splat(c.y),  x);
    return x;
}

__device__ __forceinline__ f32x2 finish_col(f32x2 x)
{
    f32x2 tt = __builtin_elementwise_fma(x, x, splat(-1.0f));
    tt = __builtin_elementwise_max(tt, splat(0.0f));
    f32x2 s  = (f32x2){fsqrt(tt.x), fsqrt(tt.y)};
    f32x2 y  = x + s;
    f32x2 L  = (f32x2){flog2(y.x), flog2(y.y)};
    f32x2 dd = __builtin_elementwise_fma(L, splat(LN2), splat(1.0f));
    f32x2 sim = (f32x2){frcp(dd.x), frcp(dd.y)};
    f32x2 arg = sim * splat(TWO_LOG2E);
    return (f32x2){fexp2(arg.x), fexp2(arg.y)};
}

// ---- symmetric pair kernel: 2-column interleaved, pk-fp32, DPP reduce ----
__global__ __launch_bounds__(BLOCK, 8) void pair_kernel(
    const float* __restrict__ q, float* __restrict__ denom)
{
    __shared__ float sq[JC * QS];       // 1.5 KB j-chunk Q
    __shared__ float sdenom[JC];        // column accumulators

    const int tid = threadIdx.x;

    // tile decode: t -> (b = i-block of 512 rows, jbase)
    const int t = blockIdx.x;
    int b = 0;
    #pragma unroll
    for (int k = 1; k < 16; ++k)
        b += (t >= (256 * k - 8 * k * (k - 1))) ? 1 : 0;
    const int Fb    = 256 * b - 8 * b * (b - 1);
    const int ibase = 512 * b;
    const int jbase = ibase + 32 * (t - Fb);
    const bool diag = (jbase < ibase + 512);

    // stage j-chunk Q (96 float4) + zero column accumulators
    if (tid < JC * QS / 4)
        ((float4*)sq)[tid] = ((const float4*)(q + (size_t)jbase * QS))[tid];
    if (tid < JC) sdenom[tid] = 0.0f;

    // own two rows -> packed P: p2[k] = {P_row0[k], P_row1[k]}
    const int irow0 = ibase + tid;
    const int irow1 = ibase + tid + BLOCK;
    f32x2 p2[10];
    {
        const float* q0 = q + (size_t)irow0 * QS;
        const float* q1 = q + (size_t)irow1 * QS;
        float4 a0 = *(const float4*)(q0), b0 = *(const float4*)(q0 + 4);
        float4 c0 = *(const float4*)(q0 + 8);
        float4 a1 = *(const float4*)(q1), b1 = *(const float4*)(q1 + 4);
        float4 c1 = *(const float4*)(q1 + 8);
        float m0 = -4.0f * c0.x, m1 = -4.0f * c1.x;
        p2[0] = (f32x2){m0 * a0.x, m1 * a1.x};
        p2[1] = (f32x2){m0 * a0.y, m1 * a1.y};
        p2[2] = (f32x2){m0 * a0.z, m1 * a1.z};
        p2[3] = (f32x2){m0 * a0.w, m1 * a1.w};
        p2[4] = (f32x2){m0 * b0.x, m1 * b1.x};
        p2[5] = (f32x2){m0 * b0.y, m1 * b1.y};
        p2[6] = (f32x2){m0 * b0.z, m1 * b1.z};
        p2[7] = (f32x2){m0 * b0.w, m1 * b1.w};
        p2[8] = (f32x2){2.0f * c0.y, 2.0f * c1.y};
        p2[9] = (f32x2){2.0f * c0.x, 2.0f * c1.x};
    }
    f32x2 acc2 = splat(0.0f);
    __syncthreads();

    #pragma unroll 2
    for (int jp = 0; jp < JC / 2; ++jp) {
        const int jj0 = 2 * jp, jj1 = 2 * jp + 1;

        // two independent chains, explicitly interleaved by the scheduler
        f32x2 x0 = pair_col(p2, sq + jj0 * QS);
        f32x2 x1 = pair_col(p2, sq + jj1 * QS);
        f32x2 e0 = finish_col(x0);
        f32x2 e1 = finish_col(x1);

        if (diag) {
            const int j0 = jbase + jj0, j1 = jbase + jj1;
            e0.x = (j0 > irow0) ? e0.x : 0.0f;
            e0.y = (j0 > irow1) ? e0.y : 0.0f;
            e1.x = (j1 > irow0) ? e1.x : 0.0f;
            e1.y = (j1 > irow1) ? e1.y : 0.0f;
        }
        acc2 += e0;
        acc2 += e1;

        float c0 = dpp_wave_sum(e0.x + e0.y);
        float c1 = dpp_wave_sum(e1.x + e1.y);
        if ((tid & 63) == 63) {
            atomicAdd(&sdenom[jj0], c0);
            atomicAdd(&sdenom[jj1], c1);
        }
    }

    __syncthreads();
    if (tid < JC) atomicAdd(&denom[jbase + tid], sdenom[tid]);
    atomicAdd(&denom[irow0], acc2.x);
    atomicAdd(&denom[irow1], acc2.y);
}

// ---- epilogue: 8 blocks x 1024, one row/thread; denom excludes self ----
__global__ __launch_bounds__(1024) void reduce_kernel(
    const float* __restrict__ zi, const float* __restrict__ zj,
    const float* __restrict__ denom, float* __restrict__ out)
{
    __shared__ float s_red[1024];
    const int tid = threadIdx.x;
    const int i   = blockIdx.x * 1024 + tid;

    const int base = (i < HALF_N) ? i : (i - HALF_N);
    const float* pa = (i < HALF_N) ? (zi + (size_t)base * D) : (zj + (size_t)base * D);
    const float* pb = (i < HALF_N) ? (zj + (size_t)base * D) : (zi + (size_t)base * D);
    float4 a0 = *(const float4*)(pa), a1 = *(const float4*)(pa + 4);
    float4 b0 = *(const float4*)(pb), b1 = *(const float4*)(pb + 4);
    float rawa = a0.x*a0.x + a0.y*a0.y + a0.z*a0.z + a0.w*a0.w
               + a1.x*a1.x + a1.y*a1.y + a1.z*a1.z + a1.w*a1.w;
    float rawb = b0.x*b0.x + b0.y*b0.y + b0.z*b0.z + b0.w*b0.w
               + b1.x*b1.x + b1.y*b1.y + b1.z*b1.z + b1.w*b1.w;
    float dot  = a0.x*b0.x + a0.y*b0.y + a0.z*b0.z + a0.w*b0.w
               + a1.x*b1.x + a1.y*b1.y + a1.z*b1.z + a1.w*b1.w;
    float sqd  = fmaxf(rawa + rawb - 2.0f * dot, 0.0f);
    float inva = frcp(1.0f - fminf(rawa, BOUNDARY));
    float invb = frcp(1.0f - fminf(rawb, BOUNDARY));
    float x    = fmaf(2.0f * sqd, inva * invb, 1.0f);
    float t    = fmaf(x, x, -1.0f);
    float s    = fsqrt(fmaxf(t, 0.0f));
    float dist = flog2(x + s) * LN2;
    float sim  = frcp(1.0f + dist);               // positive pair similarity
    float dlog = flog2(denom[i]) * LN2;           // self already excluded
    float term = -(2.0f * sim - dlog);

    s_red[tid] = term;
    __syncthreads();
    for (int off = 512; off > 0; off >>= 1) {
        if (tid < off) s_red[tid] += s_red[tid + off];
        __syncthreads();
    }
    if (tid == 0) atomicAdd(out, s_red[0] * (1.0f / (float)TWO_N));
}

extern "C" void kernel_launch(void* const* d_in, const int* in_sizes, int n_in,
                              void* d_out, int out_size, void* d_ws, size_t ws_size,
                              hipStream_t stream) {
    const float* zi = (const float*)d_in[0];
    const float* zj = (const float*)d_in[1];

    float* denom = (float*)d_ws;                  // [8192]
    float* q     = denom + TWO_N;                 // [8192 * 12]

    prep_kernel<<<TWO_N / 256, 256, 0, stream>>>(zi, zj, q, denom, (float*)d_out);

    pair_kernel<<<NTILE, BLOCK, 0, stream>>>(q, denom);

    reduce_kernel<<<TWO_N / 1024, 1024, 0, stream>>>(zi, zj, denom, (float*)d_out);
}